// Round 4
// baseline (221.078 us; speedup 1.0000x reference)
//
#include <hip/hip_runtime.h>
#include <hip/hip_bf16.h>

#define N_PIX 196608
#define KNN 32
#define BATCH 8
// CHANNELS = 4 (float4)

// ws layout:
//   [0, N_PIX*32*4)                : xs = x transposed to (N,B,C) * inv_rowsum[n]
//   [XS_BYTES, +4)                 : int flag (1 = inds are int64, 0 = int32)
#define XS_BYTES ((size_t)N_PIX * 32 * 4)

// Fused: int64-detect + rowsum + scale + transpose.  Block handles 32 pixels.
// xs[n, b, c] = x[b, n, c] / rowsum[n]   (one 128B line per source pixel)
__global__ __launch_bounds__(256) void k_prep(const float* __restrict__ x,
                                              const float* __restrict__ kern,
                                              const unsigned int* __restrict__ inds_u32,
                                              float* __restrict__ xs,
                                              int* __restrict__ flag) {
    // detect: odd 32-bit words of first 64 index entries all zero => int64
    if (blockIdx.x == 0 && threadIdx.x < 64) {
        unsigned int v = inds_u32[threadIdx.x * 2 + 1];
        unsigned long long bal = __ballot(v != 0);
        if (threadIdx.x == 0) *flag = (bal == 0ULL) ? 1 : 0;
    }

    __shared__ float s_inv[32];
    __shared__ float4 tile[32][9];                   // +1 pad to break bank conflicts
    int n0 = blockIdx.x * 32;
    int t = threadIdx.x;

    // rowsum: 8 lanes per pixel, float4 each
    const float4* kv = reinterpret_cast<const float4*>(kern);
    float4 v = kv[(size_t)(n0 + (t >> 3)) * 8 + (t & 7)];
    float s = v.x + v.y + v.z + v.w;
    s += __shfl_xor(s, 1);
    s += __shfl_xor(s, 2);
    s += __shfl_xor(s, 4);
    if ((t & 7) == 0) s_inv[t >> 3] = 1.0f / s;
    __syncthreads();

    // scale + stage transpose
    int b = t >> 5, i = t & 31;
    const float4* xv = reinterpret_cast<const float4*>(x);
    float4 u = xv[(size_t)b * N_PIX + n0 + i];       // coalesced read
    float r = s_inv[i];
    u.x *= r; u.y *= r; u.z *= r; u.w *= r;
    tile[i][b] = u;
    __syncthreads();

    int row = t >> 3, bb = t & 7;
    reinterpret_cast<float4*>(xs)[(size_t)(n0 + row) * 8 + bb] = tile[row][bb];
}

// Thread per (n, b): acc[n,b,:] = sum_k kern[n,k] * xs[j(n,k), b, :]
// Lanes 0..7 of each 8-lane group share n (and so j) -> one coalesced 128B
// segment per group per gather instruction.
// STRIDE = bytes per index element (8 for int64, 4 for int32); we read only
// the low dword (indices < 2^31, little-endian).
template <int STRIDE>
__device__ __forceinline__ void main_body(int n, int b, const float* __restrict__ kern,
                                          const char* __restrict__ ipb,
                                          const float4* __restrict__ xsv,
                                          float4* __restrict__ ov) {
    const float4* wv = reinterpret_cast<const float4*>(kern) + (size_t)n * 8;
    float4 acc = make_float4(0.f, 0.f, 0.f, 0.f);

#pragma unroll 2
    for (int k0 = 0; k0 < KNN; k0 += 4) {
        int j[4];
#pragma unroll
        for (int u = 0; u < 4; ++u)
            j[u] = *reinterpret_cast<const int*>(ipb + (size_t)(k0 + u) * STRIDE);
        float4 wq = wv[k0 >> 2];
        float w[4] = {wq.x, wq.y, wq.z, wq.w};

        float4 sv[4];
#pragma unroll
        for (int u = 0; u < 4; ++u) sv[u] = xsv[(size_t)j[u] * 8 + b];
#pragma unroll
        for (int u = 0; u < 4; ++u) {
            acc.x = fmaf(w[u], sv[u].x, acc.x);
            acc.y = fmaf(w[u], sv[u].y, acc.y);
            acc.z = fmaf(w[u], sv[u].z, acc.z);
            acc.w = fmaf(w[u], sv[u].w, acc.w);
        }
    }
    ov[(size_t)b * N_PIX + n] = acc;
}

__global__ __launch_bounds__(256, 8) void k_main(const float* __restrict__ kern,
                                                 const void* __restrict__ inds,
                                                 const float* __restrict__ xs,
                                                 const int* __restrict__ flag,
                                                 float* __restrict__ out) {
    int tid = blockIdx.x * 256 + threadIdx.x;        // [0, N_PIX*8)
    int n = tid >> 3;
    int b = tid & 7;
    const float4* xsv = reinterpret_cast<const float4*>(xs);
    float4* ov = reinterpret_cast<float4*>(out);
    const char* base = reinterpret_cast<const char*>(inds);
    if (*flag) {
        main_body<8>(n, b, kern, base + (size_t)n * KNN * 8, xsv, ov);
    } else {
        main_body<4>(n, b, kern, base + (size_t)n * KNN * 4, xsv, ov);
    }
}

extern "C" void kernel_launch(void* const* d_in, const int* in_sizes, int n_in,
                              void* d_out, int out_size, void* d_ws, size_t ws_size,
                              hipStream_t stream) {
    const float* x    = (const float*)d_in[0];
    const float* kern = (const float*)d_in[1];
    const void*  inds = d_in[2];
    float* out = (float*)d_out;

    float* xs   = (float*)d_ws;
    int*   flag = (int*)((char*)d_ws + XS_BYTES);

    k_prep<<<N_PIX / 32, 256, 0, stream>>>(x, kern, (const unsigned int*)inds, xs, flag);
    k_main<<<(N_PIX * BATCH) / 256, 256, 0, stream>>>(kern, inds, xs, flag, out);
}

// Round 10
// 210.681 us; speedup vs baseline: 1.0494x; 1.0494x over previous
//
#include <hip/hip_runtime.h>
#include <hip/hip_bf16.h>
#include <hip/hip_fp16.h>

#define N_PIX 196608
#define KNN 32
#define BATCH 8
// CHANNELS = 4

typedef float f4v __attribute__((ext_vector_type(4)));   // nontemporal-compatible

// ws layout:
//   [0, N_PIX*32*2)                : xs = x transposed to (N,B,C), scaled, fp16
//   [XS_BYTES, +4)                 : int flag (1 = inds are int64, 0 = int32)
#define XS_BYTES ((size_t)N_PIX * 32 * 2)

__device__ __forceinline__ unsigned int pack_h2(float a, float b) {
    __half2 h = __floats2half2_rn(a, b);
    return *reinterpret_cast<unsigned int*>(&h);
}

// Fused: int64-detect + rowsum + scale + transpose. Block handles 32 pixels.
// xs[n, b, c] = fp16( x[b, n, c] / rowsum[n] )  -> 64 B per source pixel
__global__ __launch_bounds__(256) void k_prep(const float* __restrict__ x,
                                              const float* __restrict__ kern,
                                              const unsigned int* __restrict__ inds_u32,
                                              uint2* __restrict__ xs,
                                              int* __restrict__ flag) {
    // detect: odd 32-bit words of first 64 index entries all zero => int64
    if (blockIdx.x == 0 && threadIdx.x < 64) {
        unsigned int v = inds_u32[threadIdx.x * 2 + 1];
        unsigned long long bal = __ballot(v != 0);
        if (threadIdx.x == 0) *flag = (bal == 0ULL) ? 1 : 0;
    }

    __shared__ float s_inv[32];
    __shared__ uint2 tile[32][9];                    // +1 pad to break bank conflicts
    int n0 = blockIdx.x * 32;
    int t = threadIdx.x;

    // rowsum: 8 lanes per pixel, float4 each
    const float4* kv = reinterpret_cast<const float4*>(kern);
    float4 v = kv[(size_t)(n0 + (t >> 3)) * 8 + (t & 7)];
    float s = v.x + v.y + v.z + v.w;
    s += __shfl_xor(s, 1);
    s += __shfl_xor(s, 2);
    s += __shfl_xor(s, 4);
    if ((t & 7) == 0) s_inv[t >> 3] = 1.0f / s;
    __syncthreads();

    // scale + convert + stage transpose
    int b = t >> 5, i = t & 31;
    const float4* xv = reinterpret_cast<const float4*>(x);
    float4 u = xv[(size_t)b * N_PIX + n0 + i];       // coalesced read
    float r = s_inv[i];
    uint2 p;
    p.x = pack_h2(u.x * r, u.y * r);
    p.y = pack_h2(u.z * r, u.w * r);
    tile[i][b] = p;
    __syncthreads();

    int row = t >> 3, bb = t & 7;
    xs[(size_t)(n0 + row) * 8 + bb] = tile[row][bb]; // coalesced 2KB per block
}

// Thread per (n, b): acc[n,b,:] = sum_k kern[n,k] * xs[j(n,k), b, :]
// Lanes 0..7 of each 8-lane group share n (and j) -> one coalesced 64B
// segment per group per gather instruction.
// STRIDE = bytes per index element (8 for int64, 4 for int32); read only the
// low dword (indices < 2^31, little-endian).
template <int STRIDE>
__device__ __forceinline__ void main_body(int n, int b, const float* __restrict__ kern,
                                          const char* __restrict__ ipb,
                                          const uint2* __restrict__ xsv,
                                          float* __restrict__ out) {
    const f4v* wv = reinterpret_cast<const f4v*>(kern) + (size_t)n * 8;
    f4v acc = (f4v)0.0f;

#pragma unroll 2
    for (int k0 = 0; k0 < KNN; k0 += 4) {
        int j[4];
#pragma unroll
        for (int u = 0; u < 4; ++u)
            j[u] = __builtin_nontemporal_load(
                reinterpret_cast<const int*>(ipb + (size_t)(k0 + u) * STRIDE));
        f4v wq = __builtin_nontemporal_load(wv + (k0 >> 2));

        uint2 g[4];
#pragma unroll
        for (int u = 0; u < 4; ++u) g[u] = xsv[(size_t)j[u] * 8 + b];  // cached
#pragma unroll
        for (int u = 0; u < 4; ++u) {
            float2 f0 = __half22float2(*reinterpret_cast<__half2*>(&g[u].x));
            float2 f1 = __half22float2(*reinterpret_cast<__half2*>(&g[u].y));
            float w = wq[u];
            acc[0] = fmaf(w, f0.x, acc[0]);
            acc[1] = fmaf(w, f0.y, acc[1]);
            acc[2] = fmaf(w, f1.x, acc[2]);
            acc[3] = fmaf(w, f1.y, acc[3]);
        }
    }
    __builtin_nontemporal_store(acc,
        reinterpret_cast<f4v*>(out) + ((size_t)b * N_PIX + n));
}

__global__ __launch_bounds__(256, 8) void k_main(const float* __restrict__ kern,
                                                 const void* __restrict__ inds,
                                                 const uint2* __restrict__ xs,
                                                 const int* __restrict__ flag,
                                                 float* __restrict__ out) {
    int tid = blockIdx.x * 256 + threadIdx.x;        // [0, N_PIX*8)
    int n = tid >> 3;
    int b = tid & 7;
    const char* base = reinterpret_cast<const char*>(inds);
    if (*flag) {
        main_body<8>(n, b, kern, base + (size_t)n * KNN * 8, xs, out);
    } else {
        main_body<4>(n, b, kern, base + (size_t)n * KNN * 4, xs, out);
    }
}

extern "C" void kernel_launch(void* const* d_in, const int* in_sizes, int n_in,
                              void* d_out, int out_size, void* d_ws, size_t ws_size,
                              hipStream_t stream) {
    const float* x    = (const float*)d_in[0];
    const float* kern = (const float*)d_in[1];
    const void*  inds = d_in[2];
    float* out = (float*)d_out;

    uint2* xs  = (uint2*)d_ws;
    int*  flag = (int*)((char*)d_ws + XS_BYTES);

    k_prep<<<N_PIX / 32, 256, 0, stream>>>(x, kern, (const unsigned int*)inds, xs, flag);
    k_main<<<(N_PIX * BATCH) / 256, 256, 0, stream>>>(kern, inds, xs, flag, out);
}